// Round 1
// baseline (3416.922 us; speedup 1.0000x reference)
//
#include <hip/hip_runtime.h>
#include <cstdint>
#include <cstddef>

#define U_NODES 100000
#define V_NODES 50000
#define N_EDGES 2000000

// dims: F=32 (u), G=32 (v), H=8 (edge); g: 72->64->32 ; f: 64->64->32 ; tail 32->1

__device__ __forceinline__ void load8f(const float* __restrict__ p, float* x) {
    const float4* p4 = reinterpret_cast<const float4*>(p);
    float4 a = p4[0], b = p4[1];
    x[0]=a.x; x[1]=a.y; x[2]=a.z; x[3]=a.w;
    x[4]=b.x; x[5]=b.y; x[6]=b.z; x[7]=b.w;
}

__device__ __forceinline__ void load32f(const float* __restrict__ p, float* x) {
    #pragma unroll
    for (int q = 0; q < 4; ++q) load8f(p + 8*q, x + 8*q);
}

// A[n][j] = sum_i u[n][i] * g_w1[i][j]           (rows 0..31 of g_w1)
__global__ __launch_bounds__(256) void proj_u_kernel(
    const float* __restrict__ u, const float* __restrict__ g_w1,
    float* __restrict__ A)
{
    int n = blockIdx.x * 256 + threadIdx.x;
    if (n >= U_NODES) return;
    float x[32];
    load32f(u + (size_t)n * 32, x);
    float acc[64];
    #pragma unroll
    for (int j = 0; j < 64; ++j) acc[j] = 0.f;
    #pragma unroll
    for (int i = 0; i < 32; ++i) {
        #pragma unroll
        for (int j = 0; j < 64; ++j) acc[j] += x[i] * g_w1[i*64 + j];
    }
    float4* Ap = reinterpret_cast<float4*>(A + (size_t)n * 64);
    #pragma unroll
    for (int q = 0; q < 16; ++q)
        Ap[q] = make_float4(acc[4*q], acc[4*q+1], acc[4*q+2], acc[4*q+3]);
}

// B[n][j] = g_b1[j] + sum_i v[n][i] * g_w1[32+i][j]   (bias folded here)
__global__ __launch_bounds__(256) void proj_v_kernel(
    const float* __restrict__ v, const float* __restrict__ g_w1,
    const float* __restrict__ g_b1, float* __restrict__ B)
{
    int n = blockIdx.x * 256 + threadIdx.x;
    if (n >= V_NODES) return;
    float x[32];
    load32f(v + (size_t)n * 32, x);
    float acc[64];
    #pragma unroll
    for (int j = 0; j < 64; ++j) acc[j] = g_b1[j];
    #pragma unroll
    for (int i = 0; i < 32; ++i) {
        #pragma unroll
        for (int j = 0; j < 64; ++j) acc[j] += x[i] * g_w1[(32+i)*64 + j];
    }
    float4* Bp = reinterpret_cast<float4*>(B + (size_t)n * 64);
    #pragma unroll
    for (int q = 0; q < 16; ++q)
        Bp[q] = make_float4(acc[4*q], acc[4*q+1], acc[4*q+2], acc[4*q+3]);
}

// h1 = relu(A[d] + B[s] + ev @ W1e); h2 = relu(h1 @ W2 + b2); atomic agg[d] += h2
__global__ __launch_bounds__(256) void edge_pre_kernel(
    const float* __restrict__ A, const float* __restrict__ B,
    const float* __restrict__ e_vals, const int* __restrict__ e_src,
    const int* __restrict__ e_dst, const float* __restrict__ g_w1,
    const float* __restrict__ g_w2, const float* __restrict__ g_b2,
    float* __restrict__ agg)
{
    int e = blockIdx.x * 256 + threadIdx.x;
    if (e >= N_EDGES) return;
    int d = e_dst[e];
    int s = e_src[e];

    float h1[64];
    const float4* Ap = reinterpret_cast<const float4*>(A + (size_t)d * 64);
    const float4* Bp = reinterpret_cast<const float4*>(B + (size_t)s * 64);
    #pragma unroll
    for (int q = 0; q < 16; ++q) {
        float4 a = Ap[q]; float4 b = Bp[q];
        h1[4*q+0] = a.x + b.x; h1[4*q+1] = a.y + b.y;
        h1[4*q+2] = a.z + b.z; h1[4*q+3] = a.w + b.w;
    }
    float ev[8];
    load8f(e_vals + (size_t)e * 8, ev);
    #pragma unroll
    for (int i = 0; i < 8; ++i) {
        #pragma unroll
        for (int j = 0; j < 64; ++j) h1[j] += ev[i] * g_w1[(64+i)*64 + j];
    }
    #pragma unroll
    for (int j = 0; j < 64; ++j) h1[j] = fmaxf(h1[j], 0.f);

    float acc2[32];
    #pragma unroll
    for (int k = 0; k < 32; ++k) acc2[k] = g_b2[k];
    #pragma unroll
    for (int i = 0; i < 64; ++i) {
        #pragma unroll
        for (int k = 0; k < 32; ++k) acc2[k] += h1[i] * g_w2[i*32 + k];
    }
    float* aggp = agg + (size_t)d * 32;
    #pragma unroll
    for (int k = 0; k < 32; ++k) atomicAdd(aggp + k, fmaxf(acc2[k], 0.f));
}

// Fallback (ws too small for A/B): full fused per-edge MLP 72->64->32
__global__ __launch_bounds__(256) void edge_direct_kernel(
    const float* __restrict__ u, const float* __restrict__ v,
    const float* __restrict__ e_vals, const int* __restrict__ e_src,
    const int* __restrict__ e_dst, const float* __restrict__ g_w1,
    const float* __restrict__ g_b1, const float* __restrict__ g_w2,
    const float* __restrict__ g_b2, float* __restrict__ agg)
{
    int e = blockIdx.x * 256 + threadIdx.x;
    if (e >= N_EDGES) return;
    int d = e_dst[e];
    int s = e_src[e];
    float x[72];
    load32f(u + (size_t)d * 32, x);
    load32f(v + (size_t)s * 32, x + 32);
    load8f(e_vals + (size_t)e * 8, x + 64);
    float h1[64];
    #pragma unroll
    for (int j = 0; j < 64; ++j) h1[j] = g_b1[j];
    #pragma unroll
    for (int i = 0; i < 72; ++i) {
        #pragma unroll
        for (int j = 0; j < 64; ++j) h1[j] += x[i] * g_w1[i*64 + j];
    }
    #pragma unroll
    for (int j = 0; j < 64; ++j) h1[j] = fmaxf(h1[j], 0.f);
    float acc2[32];
    #pragma unroll
    for (int k = 0; k < 32; ++k) acc2[k] = g_b2[k];
    #pragma unroll
    for (int i = 0; i < 64; ++i) {
        #pragma unroll
        for (int k = 0; k < 32; ++k) acc2[k] += h1[i] * g_w2[i*32 + k];
    }
    float* aggp = agg + (size_t)d * 32;
    #pragma unroll
    for (int k = 0; k < 32; ++k) atomicAdd(aggp + k, fmaxf(acc2[k], 0.f));
}

// z1 = relu([u, agg] @ f_w1 + f_b1); z2 = relu(z1 @ f_w2 + f_b2); out = sigmoid(z2 @ t_w + t_b)
__global__ __launch_bounds__(256) void node_kernel(
    const float* __restrict__ u, const float* __restrict__ agg,
    const float* __restrict__ f_w1, const float* __restrict__ f_b1,
    const float* __restrict__ f_w2, const float* __restrict__ f_b2,
    const float* __restrict__ t_w, const float* __restrict__ t_b,
    float* __restrict__ out)
{
    int n = blockIdx.x * 256 + threadIdx.x;
    if (n >= U_NODES) return;
    float x[64];
    load32f(u   + (size_t)n * 32, x);
    load32f(agg + (size_t)n * 32, x + 32);
    float z1[64];
    #pragma unroll
    for (int j = 0; j < 64; ++j) z1[j] = f_b1[j];
    #pragma unroll
    for (int i = 0; i < 64; ++i) {
        #pragma unroll
        for (int j = 0; j < 64; ++j) z1[j] += x[i] * f_w1[i*64 + j];
    }
    #pragma unroll
    for (int j = 0; j < 64; ++j) z1[j] = fmaxf(z1[j], 0.f);
    float z2[32];
    #pragma unroll
    for (int k = 0; k < 32; ++k) z2[k] = f_b2[k];
    #pragma unroll
    for (int j = 0; j < 64; ++j) {
        #pragma unroll
        for (int k = 0; k < 32; ++k) z2[k] += z1[j] * f_w2[j*32 + k];
    }
    #pragma unroll
    for (int k = 0; k < 32; ++k) z2[k] = fmaxf(z2[k], 0.f);
    float o = t_b[0];
    #pragma unroll
    for (int k = 0; k < 32; ++k) o += z2[k] * t_w[k];
    out[n] = 1.f / (1.f + expf(-o));
}

extern "C" void kernel_launch(void* const* d_in, const int* in_sizes, int n_in,
                              void* d_out, int out_size, void* d_ws, size_t ws_size,
                              hipStream_t stream) {
    const float* u      = (const float*)d_in[0];
    const float* v      = (const float*)d_in[1];
    const float* e_vals = (const float*)d_in[2];
    const int*   e_src  = (const int*)  d_in[3];
    const int*   e_dst  = (const int*)  d_in[4];
    const float* g_w1   = (const float*)d_in[5];
    const float* g_b1   = (const float*)d_in[6];
    const float* g_w2   = (const float*)d_in[7];
    const float* g_b2   = (const float*)d_in[8];
    const float* f_w1   = (const float*)d_in[9];
    const float* f_b1   = (const float*)d_in[10];
    const float* f_w2   = (const float*)d_in[11];
    const float* f_b2   = (const float*)d_in[12];
    const float* t_w    = (const float*)d_in[13];
    const float* t_b    = (const float*)d_in[14];
    float* out = (float*)d_out;

    const size_t aggBytes = (size_t)U_NODES * 32 * sizeof(float); // 12.8 MB
    const size_t aBytes   = (size_t)U_NODES * 64 * sizeof(float); // 25.6 MB
    const size_t bBytes   = (size_t)V_NODES * 64 * sizeof(float); // 12.8 MB

    char*  wsc = (char*)d_ws;
    float* agg = (float*)wsc;
    hipMemsetAsync(agg, 0, aggBytes, stream);

    if (ws_size >= aggBytes + aBytes + bBytes) {
        float* A  = (float*)(wsc + aggBytes);
        float* Bm = (float*)(wsc + aggBytes + aBytes);
        proj_u_kernel<<<(U_NODES + 255) / 256, 256, 0, stream>>>(u, g_w1, A);
        proj_v_kernel<<<(V_NODES + 255) / 256, 256, 0, stream>>>(v, g_w1, g_b1, Bm);
        edge_pre_kernel<<<(N_EDGES + 255) / 256, 256, 0, stream>>>(
            A, Bm, e_vals, e_src, e_dst, g_w1, g_w2, g_b2, agg);
    } else {
        edge_direct_kernel<<<(N_EDGES + 255) / 256, 256, 0, stream>>>(
            u, v, e_vals, e_src, e_dst, g_w1, g_b1, g_w2, g_b2, agg);
    }
    node_kernel<<<(U_NODES + 255) / 256, 256, 0, stream>>>(
        u, agg, f_w1, f_b1, f_w2, f_b2, t_w, t_b, out);
}

// Round 2
// 3415.267 us; speedup vs baseline: 1.0005x; 1.0005x over previous
//
#include <hip/hip_runtime.h>
#include <cstdint>
#include <cstddef>

#define U_NODES 100000
#define V_NODES 50000
#define N_EDGES 2000000

// dims: F=32 (u), G=32 (v), H=8 (edge); g: 72->64->32 ; f: 64->64->32 ; tail 32->1

__device__ __forceinline__ void load8f(const float* __restrict__ p, float* x) {
    const float4* p4 = reinterpret_cast<const float4*>(p);
    float4 a = p4[0], b = p4[1];
    x[0]=a.x; x[1]=a.y; x[2]=a.z; x[3]=a.w;
    x[4]=b.x; x[5]=b.y; x[6]=b.z; x[7]=b.w;
}

__device__ __forceinline__ void load32f(const float* __restrict__ p, float* x) {
    #pragma unroll
    for (int q = 0; q < 4; ++q) load8f(p + 8*q, x + 8*q);
}

// ---------------- shared pre-projection kernels (A = u@W1u, B = v@W1v + b1) ----

__global__ __launch_bounds__(256) void proj_u_kernel(
    const float* __restrict__ u, const float* __restrict__ g_w1,
    float* __restrict__ A)
{
    int n = blockIdx.x * 256 + threadIdx.x;
    if (n >= U_NODES) return;
    float x[32];
    load32f(u + (size_t)n * 32, x);
    float acc[64];
    #pragma unroll
    for (int j = 0; j < 64; ++j) acc[j] = 0.f;
    #pragma unroll
    for (int i = 0; i < 32; ++i) {
        #pragma unroll
        for (int j = 0; j < 64; ++j) acc[j] += x[i] * g_w1[i*64 + j];
    }
    float4* Ap = reinterpret_cast<float4*>(A + (size_t)n * 64);
    #pragma unroll
    for (int q = 0; q < 16; ++q)
        Ap[q] = make_float4(acc[4*q], acc[4*q+1], acc[4*q+2], acc[4*q+3]);
}

__global__ __launch_bounds__(256) void proj_v_kernel(
    const float* __restrict__ v, const float* __restrict__ g_w1,
    const float* __restrict__ g_b1, float* __restrict__ B)
{
    int n = blockIdx.x * 256 + threadIdx.x;
    if (n >= V_NODES) return;
    float x[32];
    load32f(v + (size_t)n * 32, x);
    float acc[64];
    #pragma unroll
    for (int j = 0; j < 64; ++j) acc[j] = g_b1[j];
    #pragma unroll
    for (int i = 0; i < 32; ++i) {
        #pragma unroll
        for (int j = 0; j < 64; ++j) acc[j] += x[i] * g_w1[(32+i)*64 + j];
    }
    float4* Bp = reinterpret_cast<float4*>(B + (size_t)n * 64);
    #pragma unroll
    for (int q = 0; q < 16; ++q)
        Bp[q] = make_float4(acc[4*q], acc[4*q+1], acc[4*q+2], acc[4*q+3]);
}

// ---------------- CSR build ----------------------------------------------------

__global__ __launch_bounds__(256) void hist_kernel(
    const int* __restrict__ e_dst, int* __restrict__ deg)
{
    int e = blockIdx.x * 256 + threadIdx.x;
    if (e >= N_EDGES) return;
    atomicAdd(&deg[e_dst[e]], 1);
}

// single-block inclusive scan -> exclusive offsets, n = U_NODES
__global__ __launch_bounds__(1024) void scan_kernel(
    const int* __restrict__ deg, int* __restrict__ off, int n)
{
    __shared__ int s[1024];
    __shared__ int carry;
    if (threadIdx.x == 0) { carry = 0; off[0] = 0; }
    __syncthreads();
    for (int base = 0; base < n; base += 1024) {
        int i = base + (int)threadIdx.x;
        int x = (i < n) ? deg[i] : 0;
        s[threadIdx.x] = x;
        __syncthreads();
        for (int o = 1; o < 1024; o <<= 1) {
            int t = (threadIdx.x >= (unsigned)o) ? s[threadIdx.x - o] : 0;
            __syncthreads();
            s[threadIdx.x] += t;
            __syncthreads();
        }
        int my = s[threadIdx.x];
        int tot = s[1023];
        if (i < n) off[i + 1] = carry + my;
        __syncthreads();
        if (threadIdx.x == 0) carry += tot;
        __syncthreads();
    }
}

__global__ __launch_bounds__(256) void scatter_kernel(
    const int* __restrict__ e_dst, const int* __restrict__ off,
    int* __restrict__ cursor, int* __restrict__ sorted_eid,
    int* __restrict__ sorted_d)
{
    int e = blockIdx.x * 256 + threadIdx.x;
    if (e >= N_EDGES) return;
    int d = e_dst[e];
    int pos = off[d] + atomicAdd(&cursor[d], 1);
    sorted_eid[pos] = e;
    sorted_d[pos] = d;
}

// ---------------- edge MLP over sorted positions, h2 materialized --------------

__global__ __launch_bounds__(256) void edge_csr_kernel(
    const float* __restrict__ A, const float* __restrict__ B,
    const float* __restrict__ e_vals, const int* __restrict__ e_src,
    const int* __restrict__ sorted_eid, const int* __restrict__ sorted_d,
    const float* __restrict__ g_w1, const float* __restrict__ g_w2,
    const float* __restrict__ g_b2, float* __restrict__ h2)
{
    int p = blockIdx.x * 256 + threadIdx.x;
    if (p >= N_EDGES) return;
    int eid = sorted_eid[p];
    int d   = sorted_d[p];
    int s   = e_src[eid];

    float h1[64];
    const float4* Ap = reinterpret_cast<const float4*>(A + (size_t)d * 64);
    const float4* Bp = reinterpret_cast<const float4*>(B + (size_t)s * 64);
    #pragma unroll
    for (int q = 0; q < 16; ++q) {
        float4 a = Ap[q]; float4 b = Bp[q];
        h1[4*q+0] = a.x + b.x; h1[4*q+1] = a.y + b.y;
        h1[4*q+2] = a.z + b.z; h1[4*q+3] = a.w + b.w;
    }
    float ev[8];
    load8f(e_vals + (size_t)eid * 8, ev);
    #pragma unroll
    for (int i = 0; i < 8; ++i) {
        #pragma unroll
        for (int j = 0; j < 64; ++j) h1[j] += ev[i] * g_w1[(64+i)*64 + j];
    }
    #pragma unroll
    for (int j = 0; j < 64; ++j) h1[j] = fmaxf(h1[j], 0.f);

    float acc2[32];
    #pragma unroll
    for (int k = 0; k < 32; ++k) acc2[k] = g_b2[k];
    #pragma unroll
    for (int i = 0; i < 64; ++i) {
        #pragma unroll
        for (int k = 0; k < 32; ++k) acc2[k] += h1[i] * g_w2[i*32 + k];
    }
    float4* hp = reinterpret_cast<float4*>(h2 + (size_t)p * 32);
    #pragma unroll
    for (int q = 0; q < 8; ++q)
        hp[q] = make_float4(fmaxf(acc2[4*q], 0.f), fmaxf(acc2[4*q+1], 0.f),
                            fmaxf(acc2[4*q+2], 0.f), fmaxf(acc2[4*q+3], 0.f));
}

// ---------------- fused gather + f MLP + sigmoid -------------------------------

__global__ __launch_bounds__(256) void node_gather_kernel(
    const float* __restrict__ u, const float* __restrict__ h2,
    const int* __restrict__ off,
    const float* __restrict__ f_w1, const float* __restrict__ f_b1,
    const float* __restrict__ f_w2, const float* __restrict__ f_b2,
    const float* __restrict__ t_w, const float* __restrict__ t_b,
    float* __restrict__ out)
{
    int n = blockIdx.x * 256 + threadIdx.x;
    if (n >= U_NODES) return;
    int beg = off[n], end = off[n + 1];
    float acc[32];
    #pragma unroll
    for (int k = 0; k < 32; ++k) acc[k] = 0.f;
    for (int p = beg; p < end; ++p) {
        const float4* hp = reinterpret_cast<const float4*>(h2 + (size_t)p * 32);
        #pragma unroll
        for (int q = 0; q < 8; ++q) {
            float4 t = hp[q];
            acc[4*q+0] += t.x; acc[4*q+1] += t.y;
            acc[4*q+2] += t.z; acc[4*q+3] += t.w;
        }
    }
    float x[32];
    load32f(u + (size_t)n * 32, x);
    float z1[64];
    #pragma unroll
    for (int j = 0; j < 64; ++j) z1[j] = f_b1[j];
    #pragma unroll
    for (int i = 0; i < 32; ++i) {
        #pragma unroll
        for (int j = 0; j < 64; ++j) z1[j] += x[i] * f_w1[i*64 + j];
    }
    #pragma unroll
    for (int i = 0; i < 32; ++i) {
        #pragma unroll
        for (int j = 0; j < 64; ++j) z1[j] += acc[i] * f_w1[(32+i)*64 + j];
    }
    #pragma unroll
    for (int j = 0; j < 64; ++j) z1[j] = fmaxf(z1[j], 0.f);
    float z2[32];
    #pragma unroll
    for (int k = 0; k < 32; ++k) z2[k] = f_b2[k];
    #pragma unroll
    for (int j = 0; j < 64; ++j) {
        #pragma unroll
        for (int k = 0; k < 32; ++k) z2[k] += z1[j] * f_w2[j*32 + k];
    }
    #pragma unroll
    for (int k = 0; k < 32; ++k) z2[k] = fmaxf(z2[k], 0.f);
    float o = t_b[0];
    #pragma unroll
    for (int k = 0; k < 32; ++k) o += z2[k] * t_w[k];
    out[n] = 1.f / (1.f + expf(-o));
}

// ---------------- fallback kernels (atomic path) -------------------------------

__global__ __launch_bounds__(256) void edge_pre_kernel(
    const float* __restrict__ A, const float* __restrict__ B,
    const float* __restrict__ e_vals, const int* __restrict__ e_src,
    const int* __restrict__ e_dst, const float* __restrict__ g_w1,
    const float* __restrict__ g_w2, const float* __restrict__ g_b2,
    float* __restrict__ agg)
{
    int e = blockIdx.x * 256 + threadIdx.x;
    if (e >= N_EDGES) return;
    int d = e_dst[e];
    int s = e_src[e];
    float h1[64];
    const float4* Ap = reinterpret_cast<const float4*>(A + (size_t)d * 64);
    const float4* Bp = reinterpret_cast<const float4*>(B + (size_t)s * 64);
    #pragma unroll
    for (int q = 0; q < 16; ++q) {
        float4 a = Ap[q]; float4 b = Bp[q];
        h1[4*q+0] = a.x + b.x; h1[4*q+1] = a.y + b.y;
        h1[4*q+2] = a.z + b.z; h1[4*q+3] = a.w + b.w;
    }
    float ev[8];
    load8f(e_vals + (size_t)e * 8, ev);
    #pragma unroll
    for (int i = 0; i < 8; ++i) {
        #pragma unroll
        for (int j = 0; j < 64; ++j) h1[j] += ev[i] * g_w1[(64+i)*64 + j];
    }
    #pragma unroll
    for (int j = 0; j < 64; ++j) h1[j] = fmaxf(h1[j], 0.f);
    float acc2[32];
    #pragma unroll
    for (int k = 0; k < 32; ++k) acc2[k] = g_b2[k];
    #pragma unroll
    for (int i = 0; i < 64; ++i) {
        #pragma unroll
        for (int k = 0; k < 32; ++k) acc2[k] += h1[i] * g_w2[i*32 + k];
    }
    float* aggp = agg + (size_t)d * 32;
    #pragma unroll
    for (int k = 0; k < 32; ++k) atomicAdd(aggp + k, fmaxf(acc2[k], 0.f));
}

__global__ __launch_bounds__(256) void node_kernel(
    const float* __restrict__ u, const float* __restrict__ agg,
    const float* __restrict__ f_w1, const float* __restrict__ f_b1,
    const float* __restrict__ f_w2, const float* __restrict__ f_b2,
    const float* __restrict__ t_w, const float* __restrict__ t_b,
    float* __restrict__ out)
{
    int n = blockIdx.x * 256 + threadIdx.x;
    if (n >= U_NODES) return;
    float x[64];
    load32f(u   + (size_t)n * 32, x);
    load32f(agg + (size_t)n * 32, x + 32);
    float z1[64];
    #pragma unroll
    for (int j = 0; j < 64; ++j) z1[j] = f_b1[j];
    #pragma unroll
    for (int i = 0; i < 64; ++i) {
        #pragma unroll
        for (int j = 0; j < 64; ++j) z1[j] += x[i] * f_w1[i*64 + j];
    }
    #pragma unroll
    for (int j = 0; j < 64; ++j) z1[j] = fmaxf(z1[j], 0.f);
    float z2[32];
    #pragma unroll
    for (int k = 0; k < 32; ++k) z2[k] = f_b2[k];
    #pragma unroll
    for (int j = 0; j < 64; ++j) {
        #pragma unroll
        for (int k = 0; k < 32; ++k) z2[k] += z1[j] * f_w2[j*32 + k];
    }
    #pragma unroll
    for (int k = 0; k < 32; ++k) z2[k] = fmaxf(z2[k], 0.f);
    float o = t_b[0];
    #pragma unroll
    for (int k = 0; k < 32; ++k) o += z2[k] * t_w[k];
    out[n] = 1.f / (1.f + expf(-o));
}

// ---------------- launch -------------------------------------------------------

static inline size_t align256(size_t x) { return (x + 255) & ~(size_t)255; }

extern "C" void kernel_launch(void* const* d_in, const int* in_sizes, int n_in,
                              void* d_out, int out_size, void* d_ws, size_t ws_size,
                              hipStream_t stream) {
    const float* u      = (const float*)d_in[0];
    const float* v      = (const float*)d_in[1];
    const float* e_vals = (const float*)d_in[2];
    const int*   e_src  = (const int*)  d_in[3];
    const int*   e_dst  = (const int*)  d_in[4];
    const float* g_w1   = (const float*)d_in[5];
    const float* g_b1   = (const float*)d_in[6];
    const float* g_w2   = (const float*)d_in[7];
    const float* g_b2   = (const float*)d_in[8];
    const float* f_w1   = (const float*)d_in[9];
    const float* f_b1   = (const float*)d_in[10];
    const float* f_w2   = (const float*)d_in[11];
    const float* f_b2   = (const float*)d_in[12];
    const float* t_w    = (const float*)d_in[13];
    const float* t_b    = (const float*)d_in[14];
    float* out = (float*)d_out;

    char* wsc = (char*)d_ws;

    // CSR-path layout
    size_t o = 0;
    size_t oA   = o; o += align256((size_t)U_NODES * 64 * 4);   // 25.6 MB
    size_t oB   = o; o += align256((size_t)V_NODES * 64 * 4);   // 12.8 MB
    size_t oDeg = o; o += align256((size_t)U_NODES * 4);        // 400 KB
    size_t oCur = o; o += align256((size_t)U_NODES * 4);        // 400 KB
    size_t oOff = o; o += align256((size_t)(U_NODES + 1) * 4);  // 400 KB
    size_t oEid = o; o += align256((size_t)N_EDGES * 4);        // 8 MB
    size_t oDs  = o; o += align256((size_t)N_EDGES * 4);        // 8 MB
    size_t oH2  = o; o += align256((size_t)N_EDGES * 32 * 4);   // 256 MB
    size_t csrNeed = o;

    const size_t aggBytes = (size_t)U_NODES * 32 * 4;           // 12.8 MB
    const size_t abNeed = aggBytes + (size_t)U_NODES * 64 * 4 + (size_t)V_NODES * 64 * 4;

    if (ws_size >= csrNeed) {
        float* A   = (float*)(wsc + oA);
        float* B   = (float*)(wsc + oB);
        int* deg   = (int*)(wsc + oDeg);
        int* cur   = (int*)(wsc + oCur);
        int* off   = (int*)(wsc + oOff);
        int* seid  = (int*)(wsc + oEid);
        int* sd    = (int*)(wsc + oDs);
        float* h2  = (float*)(wsc + oH2);

        hipMemsetAsync(wsc + oDeg, 0, align256((size_t)U_NODES * 4) * 2, stream); // deg+cur

        proj_u_kernel<<<(U_NODES + 255) / 256, 256, 0, stream>>>(u, g_w1, A);
        proj_v_kernel<<<(V_NODES + 255) / 256, 256, 0, stream>>>(v, g_w1, g_b1, B);
        hist_kernel<<<(N_EDGES + 255) / 256, 256, 0, stream>>>(e_dst, deg);
        scan_kernel<<<1, 1024, 0, stream>>>(deg, off, U_NODES);
        scatter_kernel<<<(N_EDGES + 255) / 256, 256, 0, stream>>>(e_dst, off, cur, seid, sd);
        edge_csr_kernel<<<(N_EDGES + 255) / 256, 256, 0, stream>>>(
            A, B, e_vals, e_src, seid, sd, g_w1, g_w2, g_b2, h2);
        node_gather_kernel<<<(U_NODES + 255) / 256, 256, 0, stream>>>(
            u, h2, off, f_w1, f_b1, f_w2, f_b2, t_w, t_b, out);
    } else if (ws_size >= abNeed) {
        float* agg = (float*)wsc;
        float* A   = (float*)(wsc + aggBytes);
        float* B   = (float*)(wsc + aggBytes + (size_t)U_NODES * 64 * 4);
        hipMemsetAsync(agg, 0, aggBytes, stream);
        proj_u_kernel<<<(U_NODES + 255) / 256, 256, 0, stream>>>(u, g_w1, A);
        proj_v_kernel<<<(V_NODES + 255) / 256, 256, 0, stream>>>(v, g_w1, g_b1, B);
        edge_pre_kernel<<<(N_EDGES + 255) / 256, 256, 0, stream>>>(
            A, B, e_vals, e_src, e_dst, g_w1, g_w2, g_b2, agg);
        node_kernel<<<(U_NODES + 255) / 256, 256, 0, stream>>>(
            u, agg, f_w1, f_b1, f_w2, f_b2, t_w, t_b, out);
    }
}

// Round 3
// 583.094 us; speedup vs baseline: 5.8600x; 5.8571x over previous
//
#include <hip/hip_runtime.h>
#include <cstdint>
#include <cstddef>

#define U_NODES 100000
#define V_NODES 50000
#define N_EDGES 2000000

// dims: F=32 (u), G=32 (v), H=8 (edge); g: 72->64->32 ; f: 64->64->32 ; tail 32->1
// g_w1 rows: [0,32) u-part, [32,64) v-part, [64,72) edge-val part.

__device__ __forceinline__ void load8f(const float* __restrict__ p, float* x) {
    const float4* p4 = reinterpret_cast<const float4*>(p);
    float4 a = p4[0], b = p4[1];
    x[0]=a.x; x[1]=a.y; x[2]=a.z; x[3]=a.w;
    x[4]=b.x; x[5]=b.y; x[6]=b.z; x[7]=b.w;
}

__device__ __forceinline__ void load32f(const float* __restrict__ p, float* x) {
    #pragma unroll
    for (int q = 0; q < 4; ++q) load8f(p + 8*q, x + 8*q);
}

// ---------------- pre-projection (A = u@W1u ; B = v@W1v + b1) ------------------

__global__ __launch_bounds__(256) void proj_u_kernel(
    const float* __restrict__ u, const float* __restrict__ g_w1,
    float* __restrict__ A)
{
    int n = blockIdx.x * 256 + threadIdx.x;
    if (n >= U_NODES) return;
    float x[32];
    load32f(u + (size_t)n * 32, x);
    float acc[64];
    #pragma unroll
    for (int j = 0; j < 64; ++j) acc[j] = 0.f;
    #pragma unroll
    for (int i = 0; i < 32; ++i) {
        #pragma unroll
        for (int j = 0; j < 64; ++j) acc[j] += x[i] * g_w1[i*64 + j];
    }
    float4* Ap = reinterpret_cast<float4*>(A + (size_t)n * 64);
    #pragma unroll
    for (int q = 0; q < 16; ++q)
        Ap[q] = make_float4(acc[4*q], acc[4*q+1], acc[4*q+2], acc[4*q+3]);
}

__global__ __launch_bounds__(256) void proj_v_kernel(
    const float* __restrict__ v, const float* __restrict__ g_w1,
    const float* __restrict__ g_b1, float* __restrict__ B)
{
    int n = blockIdx.x * 256 + threadIdx.x;
    if (n >= V_NODES) return;
    float x[32];
    load32f(v + (size_t)n * 32, x);
    float acc[64];
    #pragma unroll
    for (int j = 0; j < 64; ++j) acc[j] = g_b1[j];
    #pragma unroll
    for (int i = 0; i < 32; ++i) {
        #pragma unroll
        for (int j = 0; j < 64; ++j) acc[j] += x[i] * g_w1[(32+i)*64 + j];
    }
    float4* Bp = reinterpret_cast<float4*>(B + (size_t)n * 64);
    #pragma unroll
    for (int q = 0; q < 16; ++q)
        Bp[q] = make_float4(acc[4*q], acc[4*q+1], acc[4*q+2], acc[4*q+3]);
}

// ---------------- CSR build ----------------------------------------------------

__global__ __launch_bounds__(256) void hist_kernel(
    const int* __restrict__ e_dst, int* __restrict__ deg)
{
    int e = blockIdx.x * 256 + threadIdx.x;
    if (e >= N_EDGES) return;
    atomicAdd(&deg[e_dst[e]], 1);
}

// block-local Hillis-Steele over 256 elems; off[i+1]=incl-within-chunk; aux[blk]=total
__global__ __launch_bounds__(256) void scan_block_kernel(
    const int* __restrict__ deg, int* __restrict__ off, int* __restrict__ aux, int n)
{
    __shared__ int s[256];
    int tid = threadIdx.x;
    int i = blockIdx.x * 256 + tid;
    int x = (i < n) ? deg[i] : 0;
    s[tid] = x;
    __syncthreads();
    #pragma unroll
    for (int o = 1; o < 256; o <<= 1) {
        int t = (tid >= o) ? s[tid - o] : 0;
        __syncthreads();
        s[tid] += t;
        __syncthreads();
    }
    if (i < n) off[i + 1] = s[tid];
    if (tid == 255) aux[blockIdx.x] = s[255];
}

// single block of 512 threads: aux -> exclusive prefix (in place). nA <= 512.
__global__ __launch_bounds__(512) void scan_aux_kernel(int* __restrict__ aux, int nA)
{
    __shared__ int s[512];
    int tid = threadIdx.x;
    int x = (tid < nA) ? aux[tid] : 0;
    s[tid] = x;
    __syncthreads();
    #pragma unroll
    for (int o = 1; o < 512; o <<= 1) {
        int t = (tid >= o) ? s[tid - o] : 0;
        __syncthreads();
        s[tid] += t;
        __syncthreads();
    }
    if (tid < nA) aux[tid] = s[tid] - x;  // exclusive
}

__global__ __launch_bounds__(256) void scan_add_kernel(
    int* __restrict__ off, const int* __restrict__ aux, int n)
{
    int i = blockIdx.x * 256 + threadIdx.x;
    if (i == 0) off[0] = 0;
    if (i < n) off[i + 1] += aux[i >> 8];
}

__global__ __launch_bounds__(256) void scatter_kernel(
    const int* __restrict__ e_dst, const int* __restrict__ off,
    int* __restrict__ cursor, int* __restrict__ sorted_eid)
{
    int e = blockIdx.x * 256 + threadIdx.x;
    if (e >= N_EDGES) return;
    int d = e_dst[e];
    int pos = off[d] + atomicAdd(&cursor[d], 1);
    sorted_eid[pos] = e;
}

// ------------- edge MLP over sorted positions + LDS segmented reduce -----------
// HAS_A: A[d] precomputed; HAS_B: B[s] precomputed (B includes bias g_b1).

template <bool HAS_A, bool HAS_B>
__global__ __launch_bounds__(256) void edge_sorted_kernel(
    const float* __restrict__ A, const float* __restrict__ B,
    const float* __restrict__ u, const float* __restrict__ v,
    const float* __restrict__ e_vals, const int* __restrict__ e_src,
    const int* __restrict__ e_dst, const int* __restrict__ seid,
    const float* __restrict__ g_w1, const float* __restrict__ g_b1,
    const float* __restrict__ g_w2, const float* __restrict__ g_b2,
    float* __restrict__ agg)
{
    __shared__ float lds_h[256][36];   // stride 36: 16B-aligned rows, conflict-free col reads
    __shared__ int   lds_d[256];
    __shared__ int   lds_heads[256];   // tid | (true_head << 16)
    __shared__ int   lds_cnt;
    __shared__ int   lds_prev_d, lds_next_d;

    const int tid = threadIdx.x;
    const long p = (long)blockIdx.x * 256 + tid;

    if (tid == 0) {
        lds_cnt = 0;
        long pprev = (long)blockIdx.x * 256 - 1;
        lds_prev_d = (pprev < 0) ? -2 : e_dst[seid[pprev]];
        long pnext = (long)blockIdx.x * 256 + 256;
        lds_next_d = (pnext >= N_EDGES) ? -2 : e_dst[seid[pnext]];
    }

    int d = -1;
    if (p < N_EDGES) {
        int eid = seid[p];
        d = e_dst[eid];
        int s = e_src[eid];

        float h1[64];
        if constexpr (HAS_A) {
            const float4* Ap = reinterpret_cast<const float4*>(A + (size_t)d * 64);
            #pragma unroll
            for (int q = 0; q < 16; ++q) {
                float4 a = Ap[q];
                h1[4*q+0] = a.x; h1[4*q+1] = a.y; h1[4*q+2] = a.z; h1[4*q+3] = a.w;
            }
        } else {
            #pragma unroll
            for (int j = 0; j < 64; ++j) h1[j] = 0.f;
            float x[32];
            load32f(u + (size_t)d * 32, x);
            #pragma unroll
            for (int i = 0; i < 32; ++i) {
                #pragma unroll
                for (int j = 0; j < 64; ++j) h1[j] += x[i] * g_w1[i*64 + j];
            }
        }
        if constexpr (HAS_B) {
            const float4* Bp = reinterpret_cast<const float4*>(B + (size_t)s * 64);
            #pragma unroll
            for (int q = 0; q < 16; ++q) {
                float4 b = Bp[q];
                h1[4*q+0] += b.x; h1[4*q+1] += b.y; h1[4*q+2] += b.z; h1[4*q+3] += b.w;
            }
        } else {
            #pragma unroll
            for (int j = 0; j < 64; ++j) h1[j] += g_b1[j];
            float x[32];
            load32f(v + (size_t)s * 32, x);
            #pragma unroll
            for (int i = 0; i < 32; ++i) {
                #pragma unroll
                for (int j = 0; j < 64; ++j) h1[j] += x[i] * g_w1[(32+i)*64 + j];
            }
        }
        float ev[8];
        load8f(e_vals + (size_t)eid * 8, ev);
        #pragma unroll
        for (int i = 0; i < 8; ++i) {
            #pragma unroll
            for (int j = 0; j < 64; ++j) h1[j] += ev[i] * g_w1[(64+i)*64 + j];
        }
        #pragma unroll
        for (int j = 0; j < 64; ++j) h1[j] = fmaxf(h1[j], 0.f);

        float h2[32];
        #pragma unroll
        for (int k = 0; k < 32; ++k) h2[k] = g_b2[k];
        #pragma unroll
        for (int i = 0; i < 64; ++i) {
            #pragma unroll
            for (int k = 0; k < 32; ++k) h2[k] += h1[i] * g_w2[i*32 + k];
        }
        float4* row = reinterpret_cast<float4*>(&lds_h[tid][0]);
        #pragma unroll
        for (int q = 0; q < 8; ++q)
            row[q] = make_float4(fmaxf(h2[4*q+0], 0.f), fmaxf(h2[4*q+1], 0.f),
                                 fmaxf(h2[4*q+2], 0.f), fmaxf(h2[4*q+3], 0.f));
    }
    lds_d[tid] = d;
    __syncthreads();

    if (p < N_EDGES) {
        int prevd = (tid == 0) ? lds_prev_d : lds_d[tid - 1];
        bool true_head = (prevd != d);
        bool is_head = (tid == 0) || true_head;
        if (is_head) {
            int idx = atomicAdd(&lds_cnt, 1);
            lds_heads[idx] = tid | (true_head ? 0x10000 : 0);
        }
    }
    __syncthreads();

    const int nseg = lds_cnt;
    const int next_d = lds_next_d;
    for (int w = tid; w < nseg * 32; w += 256) {
        int seg = w >> 5, c = w & 31;
        int ent = lds_heads[seg];
        int h = ent & 0xFFFF;
        bool thead = (ent & 0x10000) != 0;
        int dd = lds_d[h];
        float sum = 0.f;
        int r = h;
        while (r < 256 && lds_d[r] == dd) { sum += lds_h[r][c]; ++r; }
        bool end_complete = (r < 256) || (next_d != dd);
        float* dst = agg + (size_t)dd * 32 + c;
        if (thead && end_complete) *dst = sum;       // sole writer for this (node, ch)
        else atomicAdd(dst, sum);                     // block-straddling segment piece
    }
}

// ---------------- node MLP (reads agg) -----------------------------------------

__global__ __launch_bounds__(256) void node_kernel(
    const float* __restrict__ u, const float* __restrict__ agg,
    const float* __restrict__ f_w1, const float* __restrict__ f_b1,
    const float* __restrict__ f_w2, const float* __restrict__ f_b2,
    const float* __restrict__ t_w, const float* __restrict__ t_b,
    float* __restrict__ out)
{
    int n = blockIdx.x * 256 + threadIdx.x;
    if (n >= U_NODES) return;
    float x[64];
    load32f(u   + (size_t)n * 32, x);
    load32f(agg + (size_t)n * 32, x + 32);
    float z1[64];
    #pragma unroll
    for (int j = 0; j < 64; ++j) z1[j] = f_b1[j];
    #pragma unroll
    for (int i = 0; i < 64; ++i) {
        #pragma unroll
        for (int j = 0; j < 64; ++j) z1[j] += x[i] * f_w1[i*64 + j];
    }
    #pragma unroll
    for (int j = 0; j < 64; ++j) z1[j] = fmaxf(z1[j], 0.f);
    float z2[32];
    #pragma unroll
    for (int k = 0; k < 32; ++k) z2[k] = f_b2[k];
    #pragma unroll
    for (int j = 0; j < 64; ++j) {
        #pragma unroll
        for (int k = 0; k < 32; ++k) z2[k] += z1[j] * f_w2[j*32 + k];
    }
    #pragma unroll
    for (int k = 0; k < 32; ++k) z2[k] = fmaxf(z2[k], 0.f);
    float o = t_b[0];
    #pragma unroll
    for (int k = 0; k < 32; ++k) o += z2[k] * t_w[k];
    out[n] = 1.f / (1.f + expf(-o));
}

// ---------------- atomic fallback (round-1 path) -------------------------------

__global__ __launch_bounds__(256) void edge_pre_kernel(
    const float* __restrict__ A, const float* __restrict__ B,
    const float* __restrict__ e_vals, const int* __restrict__ e_src,
    const int* __restrict__ e_dst, const float* __restrict__ g_w1,
    const float* __restrict__ g_w2, const float* __restrict__ g_b2,
    float* __restrict__ agg)
{
    int e = blockIdx.x * 256 + threadIdx.x;
    if (e >= N_EDGES) return;
    int d = e_dst[e];
    int s = e_src[e];
    float h1[64];
    const float4* Ap = reinterpret_cast<const float4*>(A + (size_t)d * 64);
    const float4* Bp = reinterpret_cast<const float4*>(B + (size_t)s * 64);
    #pragma unroll
    for (int q = 0; q < 16; ++q) {
        float4 a = Ap[q]; float4 b = Bp[q];
        h1[4*q+0] = a.x + b.x; h1[4*q+1] = a.y + b.y;
        h1[4*q+2] = a.z + b.z; h1[4*q+3] = a.w + b.w;
    }
    float ev[8];
    load8f(e_vals + (size_t)e * 8, ev);
    #pragma unroll
    for (int i = 0; i < 8; ++i) {
        #pragma unroll
        for (int j = 0; j < 64; ++j) h1[j] += ev[i] * g_w1[(64+i)*64 + j];
    }
    #pragma unroll
    for (int j = 0; j < 64; ++j) h1[j] = fmaxf(h1[j], 0.f);
    float acc2[32];
    #pragma unroll
    for (int k = 0; k < 32; ++k) acc2[k] = g_b2[k];
    #pragma unroll
    for (int i = 0; i < 64; ++i) {
        #pragma unroll
        for (int k = 0; k < 32; ++k) acc2[k] += h1[i] * g_w2[i*32 + k];
    }
    float* aggp = agg + (size_t)d * 32;
    #pragma unroll
    for (int k = 0; k < 32; ++k) atomicAdd(aggp + k, fmaxf(acc2[k], 0.f));
}

// ---------------- launch -------------------------------------------------------

static inline size_t align256(size_t x) { return (x + 255) & ~(size_t)255; }

extern "C" void kernel_launch(void* const* d_in, const int* in_sizes, int n_in,
                              void* d_out, int out_size, void* d_ws, size_t ws_size,
                              hipStream_t stream) {
    const float* u      = (const float*)d_in[0];
    const float* v      = (const float*)d_in[1];
    const float* e_vals = (const float*)d_in[2];
    const int*   e_src  = (const int*)  d_in[3];
    const int*   e_dst  = (const int*)  d_in[4];
    const float* g_w1   = (const float*)d_in[5];
    const float* g_b1   = (const float*)d_in[6];
    const float* g_w2   = (const float*)d_in[7];
    const float* g_b2   = (const float*)d_in[8];
    const float* f_w1   = (const float*)d_in[9];
    const float* f_b1   = (const float*)d_in[10];
    const float* f_w2   = (const float*)d_in[11];
    const float* f_b2   = (const float*)d_in[12];
    const float* t_w    = (const float*)d_in[13];
    const float* t_b    = (const float*)d_in[14];
    float* out = (float*)d_out;

    char* wsc = (char*)d_ws;
    const int nChunks = (U_NODES + 255) / 256;                   // 391

    // common CSR scratch
    size_t o = 0;
    size_t oDeg = o; o += align256((size_t)U_NODES * 4);         // 400 KB
    size_t oCur = o; o += align256((size_t)U_NODES * 4);         // 400 KB
    size_t oOff = o; o += align256((size_t)(U_NODES + 1) * 4);   // 400 KB
    size_t oAux = o; o += align256((size_t)nChunks * 4);         // 1.6 KB
    size_t oEid = o; o += align256((size_t)N_EDGES * 4);         // 8 MB
    size_t oAgg = o; o += align256((size_t)U_NODES * 32 * 4);    // 12.8 MB
    size_t baseNeed = o;                                         // ~22 MB
    size_t oB = o;   size_t needB  = o + align256((size_t)V_NODES * 64 * 4);  // +12.8 -> ~35 MB
    size_t oA = needB; size_t needAB = needB + align256((size_t)U_NODES * 64 * 4); // +25.6 -> ~61 MB

    if (ws_size >= baseNeed) {
        int* deg   = (int*)(wsc + oDeg);
        int* cur   = (int*)(wsc + oCur);
        int* off   = (int*)(wsc + oOff);
        int* aux   = (int*)(wsc + oAux);
        int* seid  = (int*)(wsc + oEid);
        float* agg = (float*)(wsc + oAgg);

        hipMemsetAsync(deg, 0, align256((size_t)U_NODES * 4) * 2, stream);  // deg + cur
        hipMemsetAsync(agg, 0, (size_t)U_NODES * 32 * 4, stream);

        hist_kernel<<<(N_EDGES + 255) / 256, 256, 0, stream>>>(e_dst, deg);
        scan_block_kernel<<<nChunks, 256, 0, stream>>>(deg, off, aux, U_NODES);
        scan_aux_kernel<<<1, 512, 0, stream>>>(aux, nChunks);
        scan_add_kernel<<<nChunks, 256, 0, stream>>>(off, aux, U_NODES);
        scatter_kernel<<<(N_EDGES + 255) / 256, 256, 0, stream>>>(e_dst, off, cur, seid);

        if (ws_size >= needAB) {
            float* B = (float*)(wsc + oB);
            float* A = (float*)(wsc + oA);
            proj_u_kernel<<<(U_NODES + 255) / 256, 256, 0, stream>>>(u, g_w1, A);
            proj_v_kernel<<<(V_NODES + 255) / 256, 256, 0, stream>>>(v, g_w1, g_b1, B);
            edge_sorted_kernel<true, true><<<(N_EDGES + 255) / 256, 256, 0, stream>>>(
                A, B, u, v, e_vals, e_src, e_dst, seid, g_w1, g_b1, g_w2, g_b2, agg);
        } else if (ws_size >= needB) {
            float* B = (float*)(wsc + oB);
            proj_v_kernel<<<(V_NODES + 255) / 256, 256, 0, stream>>>(v, g_w1, g_b1, B);
            edge_sorted_kernel<false, true><<<(N_EDGES + 255) / 256, 256, 0, stream>>>(
                nullptr, B, u, v, e_vals, e_src, e_dst, seid, g_w1, g_b1, g_w2, g_b2, agg);
        } else {
            edge_sorted_kernel<false, false><<<(N_EDGES + 255) / 256, 256, 0, stream>>>(
                nullptr, nullptr, u, v, e_vals, e_src, e_dst, seid, g_w1, g_b1, g_w2, g_b2, agg);
        }
        node_kernel<<<(U_NODES + 255) / 256, 256, 0, stream>>>(
            u, agg, f_w1, f_b1, f_w2, f_b2, t_w, t_b, out);
    } else {
        // atomic fallback (round-1 behavior)
        const size_t aggBytes = (size_t)U_NODES * 32 * 4;
        float* agg = (float*)wsc;
        float* A   = (float*)(wsc + aggBytes);
        float* B   = (float*)(wsc + aggBytes + (size_t)U_NODES * 64 * 4);
        hipMemsetAsync(agg, 0, aggBytes, stream);
        proj_u_kernel<<<(U_NODES + 255) / 256, 256, 0, stream>>>(u, g_w1, A);
        proj_v_kernel<<<(V_NODES + 255) / 256, 256, 0, stream>>>(v, g_w1, g_b1, B);
        edge_pre_kernel<<<(N_EDGES + 255) / 256, 256, 0, stream>>>(
            A, B, e_vals, e_src, e_dst, g_w1, g_w2, g_b2, agg);
        node_kernel<<<(U_NODES + 255) / 256, 256, 0, stream>>>(
            u, agg, f_w1, f_b1, f_w2, f_b2, t_w, t_b, out);
    }
}

// Round 4
// 469.310 us; speedup vs baseline: 7.2807x; 1.2424x over previous
//
#include <hip/hip_runtime.h>
#include <cstdint>
#include <cstddef>

#define U_NODES 100000
#define V_NODES 50000
#define N_EDGES 2000000

// dims: F=32 (u), G=32 (v), H=8 (edge); g: 72->64->32 ; f: 64->64->32 ; tail 32->1
// g_w1 rows: [0,32) u-part, [32,64) v-part, [64,72) edge-val part.

__device__ __forceinline__ void load8f(const float* __restrict__ p, float* x) {
    const float4* p4 = reinterpret_cast<const float4*>(p);
    float4 a = p4[0], b = p4[1];
    x[0]=a.x; x[1]=a.y; x[2]=a.z; x[3]=a.w;
    x[4]=b.x; x[5]=b.y; x[6]=b.z; x[7]=b.w;
}

__device__ __forceinline__ void load32f(const float* __restrict__ p, float* x) {
    #pragma unroll
    for (int q = 0; q < 4; ++q) load8f(p + 8*q, x + 8*q);
}

// RNE round two f32 to bf16, packed low|high
__device__ __forceinline__ unsigned pack_bf16x2(float a, float b) {
    unsigned ua = __float_as_uint(a);
    ua = (ua + 0x7FFFu + ((ua >> 16) & 1u)) >> 16;
    unsigned ub = __float_as_uint(b);
    ub = (ub + 0x7FFFu + ((ub >> 16) & 1u)) & 0xFFFF0000u;
    return ua | ub;
}

// ---------------- pre-projection (A = u@W1u ; B = v@W1v + b1) ------------------

__global__ __launch_bounds__(256) void proj_u_kernel(
    const float* __restrict__ u, const float* __restrict__ g_w1,
    float* __restrict__ A)
{
    int n = blockIdx.x * 256 + threadIdx.x;
    if (n >= U_NODES) return;
    float x[32];
    load32f(u + (size_t)n * 32, x);
    float acc[64];
    #pragma unroll
    for (int j = 0; j < 64; ++j) acc[j] = 0.f;
    #pragma unroll
    for (int i = 0; i < 32; ++i) {
        #pragma unroll
        for (int j = 0; j < 64; ++j) acc[j] += x[i] * g_w1[i*64 + j];
    }
    float4* Ap = reinterpret_cast<float4*>(A + (size_t)n * 64);
    #pragma unroll
    for (int q = 0; q < 16; ++q)
        Ap[q] = make_float4(acc[4*q], acc[4*q+1], acc[4*q+2], acc[4*q+3]);
}

__global__ __launch_bounds__(256) void proj_v_kernel(
    const float* __restrict__ v, const float* __restrict__ g_w1,
    const float* __restrict__ g_b1, float* __restrict__ B)
{
    int n = blockIdx.x * 256 + threadIdx.x;
    if (n >= V_NODES) return;
    float x[32];
    load32f(v + (size_t)n * 32, x);
    float acc[64];
    #pragma unroll
    for (int j = 0; j < 64; ++j) acc[j] = g_b1[j];
    #pragma unroll
    for (int i = 0; i < 32; ++i) {
        #pragma unroll
        for (int j = 0; j < 64; ++j) acc[j] += x[i] * g_w1[(32+i)*64 + j];
    }
    float4* Bp = reinterpret_cast<float4*>(B + (size_t)n * 64);
    #pragma unroll
    for (int q = 0; q < 16; ++q)
        Bp[q] = make_float4(acc[4*q], acc[4*q+1], acc[4*q+2], acc[4*q+3]);
}

// ---------------- CSR build ----------------------------------------------------

// single pass: per-edge rank within its destination bucket + histogram
__global__ __launch_bounds__(256) void rank_kernel(
    const int* __restrict__ e_dst, int* __restrict__ deg, int* __restrict__ rank)
{
    int e = blockIdx.x * 256 + threadIdx.x;
    if (e >= N_EDGES) return;
    rank[e] = atomicAdd(&deg[e_dst[e]], 1);
}

// block-local Hillis-Steele over 256 elems; off[i+1]=incl-within-chunk; aux[blk]=total
__global__ __launch_bounds__(256) void scan_block_kernel(
    const int* __restrict__ deg, int* __restrict__ off, int* __restrict__ aux, int n)
{
    __shared__ int s[256];
    int tid = threadIdx.x;
    int i = blockIdx.x * 256 + tid;
    int x = (i < n) ? deg[i] : 0;
    s[tid] = x;
    __syncthreads();
    #pragma unroll
    for (int o = 1; o < 256; o <<= 1) {
        int t = (tid >= o) ? s[tid - o] : 0;
        __syncthreads();
        s[tid] += t;
        __syncthreads();
    }
    if (i < n) off[i + 1] = s[tid];
    if (tid == 255) aux[blockIdx.x] = s[255];
}

__global__ __launch_bounds__(512) void scan_aux_kernel(int* __restrict__ aux, int nA)
{
    __shared__ int s[512];
    int tid = threadIdx.x;
    int x = (tid < nA) ? aux[tid] : 0;
    s[tid] = x;
    __syncthreads();
    #pragma unroll
    for (int o = 1; o < 512; o <<= 1) {
        int t = (tid >= o) ? s[tid - o] : 0;
        __syncthreads();
        s[tid] += t;
        __syncthreads();
    }
    if (tid < nA) aux[tid] = s[tid] - x;  // exclusive
}

__global__ __launch_bounds__(256) void scan_add_kernel(
    int* __restrict__ off, const int* __restrict__ aux, int n)
{
    int i = blockIdx.x * 256 + threadIdx.x;
    if (i == 0) off[0] = 0;
    if (i < n) off[i + 1] += aux[i >> 8];
}

// atomic-free scatter using precomputed rank
__global__ __launch_bounds__(256) void scatter_kernel(
    const int* __restrict__ e_dst, const int* __restrict__ off,
    const int* __restrict__ rank, int* __restrict__ sorted_eid)
{
    int e = blockIdx.x * 256 + threadIdx.x;
    if (e >= N_EDGES) return;
    int d = e_dst[e];
    sorted_eid[off[d] + rank[e]] = e;
}

// ------------- edge MLP over sorted positions + LDS segmented reduce -----------
// HAS_A: A[d] precomputed; HAS_B: B[s] precomputed (B includes bias g_b1).
// h2 staged in LDS as packed bf16x2 (u32) -> ~19.5 KB LDS -> ~7 WG/CU.

template <bool HAS_A, bool HAS_B>
__global__ __launch_bounds__(256) void edge_sorted_kernel(
    const float* __restrict__ A, const float* __restrict__ B,
    const float* __restrict__ u, const float* __restrict__ v,
    const float* __restrict__ e_vals, const int* __restrict__ e_src,
    const int* __restrict__ e_dst, const int* __restrict__ seid,
    const float* __restrict__ g_w1, const float* __restrict__ g_b1,
    const float* __restrict__ g_w2, const float* __restrict__ g_b2,
    float* __restrict__ agg)
{
    __shared__ unsigned lds_h[256][17];  // 16 packed bf16x2 words + 1 pad (bank spread)
    __shared__ int lds_d[256];
    __shared__ int lds_heads[256];       // tid | (true_head << 16)
    __shared__ int lds_cnt;
    __shared__ int lds_prev_d, lds_next_d;

    const int tid = threadIdx.x;
    const long p = (long)blockIdx.x * 256 + tid;

    if (tid == 0) {
        lds_cnt = 0;
        long pprev = (long)blockIdx.x * 256 - 1;
        lds_prev_d = (pprev < 0) ? -2 : e_dst[seid[pprev]];
        long pnext = (long)blockIdx.x * 256 + 256;
        lds_next_d = (pnext >= N_EDGES) ? -2 : e_dst[seid[pnext]];
    }

    int d = -1;
    if (p < N_EDGES) {
        int eid = seid[p];
        d = e_dst[eid];
        int s = e_src[eid];

        float h1[64];
        if constexpr (HAS_A) {
            const float4* Ap = reinterpret_cast<const float4*>(A + (size_t)d * 64);
            #pragma unroll
            for (int q = 0; q < 16; ++q) {
                float4 a = Ap[q];
                h1[4*q+0] = a.x; h1[4*q+1] = a.y; h1[4*q+2] = a.z; h1[4*q+3] = a.w;
            }
        } else {
            #pragma unroll
            for (int j = 0; j < 64; ++j) h1[j] = 0.f;
            float x[32];
            load32f(u + (size_t)d * 32, x);
            #pragma unroll
            for (int i = 0; i < 32; ++i) {
                #pragma unroll
                for (int j = 0; j < 64; ++j) h1[j] += x[i] * g_w1[i*64 + j];
            }
        }
        if constexpr (HAS_B) {
            const float4* Bp = reinterpret_cast<const float4*>(B + (size_t)s * 64);
            #pragma unroll
            for (int q = 0; q < 16; ++q) {
                float4 b = Bp[q];
                h1[4*q+0] += b.x; h1[4*q+1] += b.y; h1[4*q+2] += b.z; h1[4*q+3] += b.w;
            }
        } else {
            #pragma unroll
            for (int j = 0; j < 64; ++j) h1[j] += g_b1[j];
            float x[32];
            load32f(v + (size_t)s * 32, x);
            #pragma unroll
            for (int i = 0; i < 32; ++i) {
                #pragma unroll
                for (int j = 0; j < 64; ++j) h1[j] += x[i] * g_w1[(32+i)*64 + j];
            }
        }
        float ev[8];
        load8f(e_vals + (size_t)eid * 8, ev);
        #pragma unroll
        for (int i = 0; i < 8; ++i) {
            #pragma unroll
            for (int j = 0; j < 64; ++j) h1[j] += ev[i] * g_w1[(64+i)*64 + j];
        }
        #pragma unroll
        for (int j = 0; j < 64; ++j) h1[j] = fmaxf(h1[j], 0.f);

        float h2[32];
        #pragma unroll
        for (int k = 0; k < 32; ++k) h2[k] = g_b2[k];
        #pragma unroll
        for (int i = 0; i < 64; ++i) {
            #pragma unroll
            for (int k = 0; k < 32; ++k) h2[k] += h1[i] * g_w2[i*32 + k];
        }
        #pragma unroll
        for (int cp = 0; cp < 16; ++cp)
            lds_h[tid][cp] = pack_bf16x2(fmaxf(h2[2*cp], 0.f), fmaxf(h2[2*cp+1], 0.f));
    }
    lds_d[tid] = d;
    __syncthreads();

    if (p < N_EDGES) {
        int prevd = (tid == 0) ? lds_prev_d : lds_d[tid - 1];
        bool true_head = (prevd != d);
        bool is_head = (tid == 0) || true_head;
        if (is_head) {
            int idx = atomicAdd(&lds_cnt, 1);
            lds_heads[idx] = tid | (true_head ? 0x10000 : 0);
        }
    }
    __syncthreads();

    const int nseg = lds_cnt;
    const int next_d = lds_next_d;
    for (int w = tid; w < nseg * 16; w += 256) {
        int seg = w >> 4, cp = w & 15;
        int ent = lds_heads[seg];
        int h = ent & 0xFFFF;
        bool thead = (ent & 0x10000) != 0;
        int dd = lds_d[h];
        float s0 = 0.f, s1 = 0.f;
        int r = h;
        while (r < 256 && lds_d[r] == dd) {
            unsigned x = lds_h[r][cp];
            s0 += __uint_as_float(x << 16);
            s1 += __uint_as_float(x & 0xFFFF0000u);
            ++r;
        }
        bool end_complete = (r < 256) || (next_d != dd);
        float* dst = agg + (size_t)dd * 32 + 2 * cp;
        if (thead && end_complete) {
            *reinterpret_cast<float2*>(dst) = make_float2(s0, s1);  // sole writer
        } else {
            atomicAdd(dst + 0, s0);
            atomicAdd(dst + 1, s1);
        }
    }
}

// ---------------- node MLP (reads agg) -----------------------------------------

__global__ __launch_bounds__(256) void node_kernel(
    const float* __restrict__ u, const float* __restrict__ agg,
    const float* __restrict__ f_w1, const float* __restrict__ f_b1,
    const float* __restrict__ f_w2, const float* __restrict__ f_b2,
    const float* __restrict__ t_w, const float* __restrict__ t_b,
    float* __restrict__ out)
{
    int n = blockIdx.x * 256 + threadIdx.x;
    if (n >= U_NODES) return;
    float x[64];
    load32f(u   + (size_t)n * 32, x);
    load32f(agg + (size_t)n * 32, x + 32);
    float z1[64];
    #pragma unroll
    for (int j = 0; j < 64; ++j) z1[j] = f_b1[j];
    #pragma unroll
    for (int i = 0; i < 64; ++i) {
        #pragma unroll
        for (int j = 0; j < 64; ++j) z1[j] += x[i] * f_w1[i*64 + j];
    }
    #pragma unroll
    for (int j = 0; j < 64; ++j) z1[j] = fmaxf(z1[j], 0.f);
    float z2[32];
    #pragma unroll
    for (int k = 0; k < 32; ++k) z2[k] = f_b2[k];
    #pragma unroll
    for (int j = 0; j < 64; ++j) {
        #pragma unroll
        for (int k = 0; k < 32; ++k) z2[k] += z1[j] * f_w2[j*32 + k];
    }
    #pragma unroll
    for (int k = 0; k < 32; ++k) z2[k] = fmaxf(z2[k], 0.f);
    float o = t_b[0];
    #pragma unroll
    for (int k = 0; k < 32; ++k) o += z2[k] * t_w[k];
    out[n] = 1.f / (1.f + expf(-o));
}

// ---------------- last-resort atomic fallback (needs only agg) ------------------

__global__ __launch_bounds__(256) void edge_direct_kernel(
    const float* __restrict__ u, const float* __restrict__ v,
    const float* __restrict__ e_vals, const int* __restrict__ e_src,
    const int* __restrict__ e_dst, const float* __restrict__ g_w1,
    const float* __restrict__ g_b1, const float* __restrict__ g_w2,
    const float* __restrict__ g_b2, float* __restrict__ agg)
{
    int e = blockIdx.x * 256 + threadIdx.x;
    if (e >= N_EDGES) return;
    int d = e_dst[e];
    int s = e_src[e];
    float x[72];
    load32f(u + (size_t)d * 32, x);
    load32f(v + (size_t)s * 32, x + 32);
    load8f(e_vals + (size_t)e * 8, x + 64);
    float h1[64];
    #pragma unroll
    for (int j = 0; j < 64; ++j) h1[j] = g_b1[j];
    #pragma unroll
    for (int i = 0; i < 72; ++i) {
        #pragma unroll
        for (int j = 0; j < 64; ++j) h1[j] += x[i] * g_w1[i*64 + j];
    }
    #pragma unroll
    for (int j = 0; j < 64; ++j) h1[j] = fmaxf(h1[j], 0.f);
    float acc2[32];
    #pragma unroll
    for (int k = 0; k < 32; ++k) acc2[k] = g_b2[k];
    #pragma unroll
    for (int i = 0; i < 64; ++i) {
        #pragma unroll
        for (int k = 0; k < 32; ++k) acc2[k] += h1[i] * g_w2[i*32 + k];
    }
    float* aggp = agg + (size_t)d * 32;
    #pragma unroll
    for (int k = 0; k < 32; ++k) atomicAdd(aggp + k, fmaxf(acc2[k], 0.f));
}

// ---------------- launch -------------------------------------------------------

static inline size_t align256(size_t x) { return (x + 255) & ~(size_t)255; }

extern "C" void kernel_launch(void* const* d_in, const int* in_sizes, int n_in,
                              void* d_out, int out_size, void* d_ws, size_t ws_size,
                              hipStream_t stream) {
    const float* u      = (const float*)d_in[0];
    const float* v      = (const float*)d_in[1];
    const float* e_vals = (const float*)d_in[2];
    const int*   e_src  = (const int*)  d_in[3];
    const int*   e_dst  = (const int*)  d_in[4];
    const float* g_w1   = (const float*)d_in[5];
    const float* g_b1   = (const float*)d_in[6];
    const float* g_w2   = (const float*)d_in[7];
    const float* g_b2   = (const float*)d_in[8];
    const float* f_w1   = (const float*)d_in[9];
    const float* f_b1   = (const float*)d_in[10];
    const float* f_w2   = (const float*)d_in[11];
    const float* f_b2   = (const float*)d_in[12];
    const float* t_w    = (const float*)d_in[13];
    const float* t_b    = (const float*)d_in[14];
    float* out = (float*)d_out;

    char* wsc = (char*)d_ws;
    const int nChunks = (U_NODES + 255) / 256;                    // 391

    // layout: [deg][off][aux][agg][seid] | tier extras
    size_t o = 0;
    size_t oDeg  = o; o += align256((size_t)U_NODES * 4);         // 400 KB
    size_t oOff  = o; o += align256((size_t)(U_NODES + 1) * 4);   // 400 KB
    size_t oAux  = o; o += align256((size_t)nChunks * 4);         // ~1.6 KB
    size_t oAgg  = o; o += align256((size_t)U_NODES * 32 * 4);    // 12.8 MB
    size_t oSeid = o; o += align256((size_t)N_EDGES * 4);         // 8 MB
    size_t baseNeed = o;                                          // ~21.6 MB
    const size_t rankBytes = align256((size_t)N_EDGES * 4);       // 8 MB
    const size_t bBytes    = align256((size_t)V_NODES * 64 * 4);  // 12.8 MB
    const size_t aBytes    = align256((size_t)U_NODES * 64 * 4);  // 25.6 MB

    // tier1: [base][B][A]  (rank aliases A: proj_u runs after scatter)  ~60.0 MB
    // tier2: [base][B]     (rank aliases B: proj_v runs after scatter)  ~34.4 MB
    // tier3: [base][rank]                                              ~29.6 MB
    size_t need1 = baseNeed + bBytes + aBytes;
    size_t need2 = baseNeed + bBytes;
    size_t need3 = baseNeed + rankBytes;

    if (ws_size >= need3) {
        int* deg   = (int*)(wsc + oDeg);
        int* off   = (int*)(wsc + oOff);
        int* aux   = (int*)(wsc + oAux);
        int* seid  = (int*)(wsc + oSeid);
        float* agg = (float*)(wsc + oAgg);

        float* B = nullptr; float* A = nullptr; int* rank;
        bool hasA = false, hasB = false;
        if (ws_size >= need1) {
            B = (float*)(wsc + baseNeed);
            A = (float*)(wsc + baseNeed + bBytes);
            rank = (int*)A;                      // aliased; A written after scatter
            hasA = hasB = true;
        } else if (ws_size >= need2) {
            B = (float*)(wsc + baseNeed);
            rank = (int*)B;                      // aliased; B written after scatter
            hasB = true;
        } else {
            rank = (int*)(wsc + baseNeed);
        }

        hipMemsetAsync(deg, 0, (size_t)U_NODES * 4, stream);
        hipMemsetAsync(agg, 0, (size_t)U_NODES * 32 * 4, stream);

        rank_kernel<<<(N_EDGES + 255) / 256, 256, 0, stream>>>(e_dst, deg, rank);
        scan_block_kernel<<<nChunks, 256, 0, stream>>>(deg, off, aux, U_NODES);
        scan_aux_kernel<<<1, 512, 0, stream>>>(aux, nChunks);
        scan_add_kernel<<<nChunks, 256, 0, stream>>>(off, aux, U_NODES);
        scatter_kernel<<<(N_EDGES + 255) / 256, 256, 0, stream>>>(e_dst, off, rank, seid);

        if (hasA) {
            proj_v_kernel<<<(V_NODES + 255) / 256, 256, 0, stream>>>(v, g_w1, g_b1, B);
            proj_u_kernel<<<(U_NODES + 255) / 256, 256, 0, stream>>>(u, g_w1, A);
            edge_sorted_kernel<true, true><<<(N_EDGES + 255) / 256, 256, 0, stream>>>(
                A, B, u, v, e_vals, e_src, e_dst, seid, g_w1, g_b1, g_w2, g_b2, agg);
        } else if (hasB) {
            proj_v_kernel<<<(V_NODES + 255) / 256, 256, 0, stream>>>(v, g_w1, g_b1, B);
            edge_sorted_kernel<false, true><<<(N_EDGES + 255) / 256, 256, 0, stream>>>(
                nullptr, B, u, v, e_vals, e_src, e_dst, seid, g_w1, g_b1, g_w2, g_b2, agg);
        } else {
            edge_sorted_kernel<false, false><<<(N_EDGES + 255) / 256, 256, 0, stream>>>(
                nullptr, nullptr, u, v, e_vals, e_src, e_dst, seid, g_w1, g_b1, g_w2, g_b2, agg);
        }
        node_kernel<<<(U_NODES + 255) / 256, 256, 0, stream>>>(
            u, agg, f_w1, f_b1, f_w2, f_b2, t_w, t_b, out);
    } else {
        // last resort: direct per-edge MLP with float atomics (agg only, 12.8 MB)
        float* agg = (float*)wsc;
        hipMemsetAsync(agg, 0, (size_t)U_NODES * 32 * 4, stream);
        edge_direct_kernel<<<(N_EDGES + 255) / 256, 256, 0, stream>>>(
            u, v, e_vals, e_src, e_dst, g_w1, g_b1, g_w2, g_b2, agg);
        node_kernel<<<(U_NODES + 255) / 256, 256, 0, stream>>>(
            u, agg, f_w1, f_b1, f_w2, f_b2, t_w, t_b, out);
    }
}